// Round 9
// baseline (131.047 us; speedup 1.0000x reference)
//
#include <hip/hip_runtime.h>
#include <stdint.h>
#include <math.h>

#define B_ 2
#define S_ 2048
#define D_ 1024
#define H_ 16
#define DK_ 64
#define M_ (B_*S_)   // 4096
#define NT_ 16       // K tiles of 64 in D_=1024

typedef unsigned short u16;
typedef unsigned int u32;
typedef __attribute__((ext_vector_type(8))) __bf16 bf16x8;
typedef __attribute__((ext_vector_type(4))) float f32x4;

#define AS1 __attribute__((address_space(1)))
#define AS3 __attribute__((address_space(3)))

__device__ __forceinline__ u16 f2bf(float f) {
  u32 u = __float_as_uint(f);
  return (u16)((u + 0x7fffu + ((u >> 16) & 1u)) >> 16);  // RNE
}
__device__ __forceinline__ u16 f2bfr(float f) {          // round-half-up (p>=0)
  return (u16)((__float_as_uint(f) + 0x8000u) >> 16);
}

__device__ __forceinline__ void gload_lds16(const void* g, void* lds) {
  __builtin_amdgcn_global_load_lds((const AS1 u32*)g,
                                   (AS3 u32*)(u32)(uintptr_t)lds, 16, 0, 0);
}

__device__ __forceinline__ f32x4 mfma16(bf16x8 a, bf16x8 b, f32x4 c) {
  return __builtin_amdgcn_mfma_f32_16x16x32_bf16(a, b, c, 0, 0, 0);
}

#define VMCNT_(n) asm volatile("s_waitcnt vmcnt(" #n ")" ::: "memory")
#define VMCNT(n) VMCNT_(n)

// ---------------- fp32 -> bf16 convert (vectorized) ----------------
__global__ __launch_bounds__(256) void f2bf_kernel(const float* __restrict__ in,
                                                   u16* __restrict__ out, int n4) {
  int i = blockIdx.x * 256 + threadIdx.x;
  if (i >= n4) return;
  float4 v = ((const float4*)in)[i];
  u32 lo = (u32)f2bf(v.x) | ((u32)f2bf(v.y) << 16);
  u32 hi = (u32)f2bf(v.z) | ((u32)f2bf(v.w) << 16);
  ((uint2*)out)[i] = make_uint2(lo, hi);
}

// fused 4-weight convert (blockIdx.y selects matrix)
__global__ __launch_bounds__(256) void f2bf4_kernel(
    const float* __restrict__ W0, const float* __restrict__ W1,
    const float* __restrict__ W2, const float* __restrict__ W3,
    u16* __restrict__ o0, u16* __restrict__ o1, u16* __restrict__ o2, u16* __restrict__ o3,
    int n4) {
  const float* src; u16* dst;
  switch (blockIdx.y) {
    case 0: src = W0; dst = o0; break;
    case 1: src = W1; dst = o1; break;
    case 2: src = W2; dst = o2; break;
    default: src = W3; dst = o3; break;
  }
  int i = blockIdx.x * 256 + threadIdx.x;
  if (i >= n4) return;
  float4 v = ((const float4*)src)[i];
  u32 lo = (u32)f2bf(v.x) | ((u32)f2bf(v.y) << 16);
  u32 hi = (u32)f2bf(v.z) | ((u32)f2bf(v.w) << 16);
  ((uint2*)dst)[i] = make_uint2(lo, hi);
}

// =============== QKV GEMM: 8-phase, operand-reuse, fused V-transpose ===============
// Round-7 schedule (operand-reuse kk-decomposition, counted vmcnt, dead-region
// staging, pre-swizzled source). Q/K (z<2): swapped mfma(bv,af) -> lane holds 4
// consecutive cols -> packed 8B row-major stores. V (z==2): UNSWAPPED mfma(af,bv)
// -> lane holds 4 consecutive ROWS (s-values) at fixed feature -> packed 8B
// stores directly into Vt[b,h,dk,s]: the transpose kernel is fused away.
__global__ __launch_bounds__(512, 2) void gemm_qkv_8ph(
    const u16* __restrict__ A,
    const u16* __restrict__ W0, const u16* __restrict__ W1, const u16* __restrict__ W2,
    const float* __restrict__ b0, const float* __restrict__ b1, const float* __restrict__ b2,
    u16* __restrict__ C0, u16* __restrict__ C1, u16* __restrict__ C2) {
  // grid = 192: xcd-major decode, my pairs per XCD for A-panel L2 locality
  const int id = blockIdx.x;
  const int xcd = id & 7, k = id >> 3;        // k 0..23
  const int my = xcd*2 + (k & 1);             // 0..15
  const int rest = k >> 1;                    // 0..11
  const int z = rest >> 2, nx = rest & 3;     // matrix, n-tile

  const u16* W = (z == 0) ? W0 : (z == 1) ? W1 : W2;
  const float* bias = (z == 0) ? b0 : (z == 1) ? b1 : b2;
  u16* C = (z == 0) ? C0 : (z == 1) ? C1 : C2;
  const float osc = (z == 0) ? 0.18033688f : 1.0f;   // Q pre-scaled: 0.125*log2(e)
  const bool vz = (z == 2);
  const int mbase = my*256, nbase = nx*256;

  __shared__ u16 LA[2][256*64];
  __shared__ u16 LB[2][256*64];

  const int tid = threadIdx.x;              // 0..511
  const int w = tid >> 6, lane = tid & 63;
  const int lo = lane & 15, hi = lane >> 4;
  const int wr = w >> 2, wc = w & 3;

  // staging geometry: local row sr (0..63), 16B chunk sc (0..7), pre-swizzled col
  const int sr = tid >> 3;
  const int sc = tid & 7;
  const int sx = (sc ^ (sr & 7)) * 8;

#define STAGE_A(buf, t, h) do {                                                   \
    int gr_ = sr + (h)*64;                                                        \
    size_t g_ = (size_t)(mbase + gr_)*D_ + (size_t)(t)*64 + sx;                   \
    gload_lds16(&A[g_],            &LA[buf][gr_*64 + sc*8]);                      \
    gload_lds16(&A[g_ + 128*D_],   &LA[buf][(gr_ + 128)*64 + sc*8]);              \
  } while (0)

#define STAGE_B(buf, t, h) do {                                                   \
    int gr_ = (sr & 31) + (h)*32 + (sr >> 5)*64;                                  \
    size_t g_ = (size_t)(nbase + gr_)*D_ + (size_t)(t)*64 + sx;                   \
    gload_lds16(&W[g_],            &LB[buf][gr_*64 + sc*8]);                      \
    gload_lds16(&W[g_ + 128*D_],   &LB[buf][(gr_ + 128)*64 + sc*8]);              \
  } while (0)

#define LDA_F(dst, buf, mq, kk) do {                                              \
    _Pragma("unroll")                                                             \
    for (int m_ = 0; m_ < 4; ++m_) {                                              \
      int R_ = wr*128 + (mq)*64 + m_*16 + lo;                                     \
      dst[m_] = *(const bf16x8*)&LA[buf][R_*64 + ((((kk)*4 + hi) ^ (R_ & 7))*8)]; \
    }                                                                             \
  } while (0)

#define LDB_F(dst, buf, kk) do {                                                  \
    _Pragma("unroll")                                                             \
    for (int q_ = 0; q_ < 2; ++q_)                                                \
      _Pragma("unroll")                                                           \
      for (int n_ = 0; n_ < 2; ++n_) {                                            \
        int R_ = wc*64 + q_*32 + n_*16 + lo;                                      \
        dst[q_][n_] =                                                             \
            *(const bf16x8*)&LB[buf][R_*64 + ((((kk)*4 + hi) ^ (R_ & 7))*8)];     \
      }                                                                           \
  } while (0)

  // Q/K: swapped (rows=n). V: unswapped (rows=m) for direct-transpose store.
#define MM(mq, af_, bv_) do {                                                     \
    __builtin_amdgcn_s_setprio(1);                                                \
    if (vz) {                                                                     \
      _Pragma("unroll")                                                           \
      for (int m_ = 0; m_ < 4; ++m_)                                              \
        _Pragma("unroll")                                                         \
        for (int q_ = 0; q_ < 2; ++q_)                                            \
          _Pragma("unroll")                                                       \
          for (int n_ = 0; n_ < 2; ++n_)                                          \
            acc[(mq)*4 + m_][q_*2 + n_] =                                         \
                mfma16(af_[m_], bv_[q_][n_], acc[(mq)*4 + m_][q_*2 + n_]);        \
    } else {                                                                      \
      _Pragma("unroll")                                                           \
      for (int m_ = 0; m_ < 4; ++m_)                                              \
        _Pragma("unroll")                                                         \
        for (int q_ = 0; q_ < 2; ++q_)                                            \
          _Pragma("unroll")                                                       \
          for (int n_ = 0; n_ < 2; ++n_)                                          \
            acc[(mq)*4 + m_][q_*2 + n_] =                                         \
                mfma16(bv_[q_][n_], af_[m_], acc[(mq)*4 + m_][q_*2 + n_]);        \
    }                                                                             \
    __builtin_amdgcn_s_setprio(0);                                                \
  } while (0)

#define BAR __builtin_amdgcn_s_barrier()

  f32x4 acc[8][4] = {};

#define TILE(buf, t) do {                                                         \
    const int tn1_ = ((t) + 1 < NT_) ? (t) + 1 : NT_ - 1;                         \
    const int tn2_ = ((t) + 2 < NT_) ? (t) + 2 : NT_ - 1;                         \
    bf16x8 af[4], bv0[2][2], bv1[2][2];                                           \
    /* P1: (mq0, kk0) */                                                          \
    LDA_F(af, buf, 0, 0); LDB_F(bv0, buf, 0);                                     \
    STAGE_B(1 - (buf), tn1_, 1);                                                  \
    BAR; MM(0, af, bv0); BAR;                                                     \
    /* P2: (mq0, kk1) */                                                          \
    LDA_F(af, buf, 0, 1); LDB_F(bv1, buf, 1);                                     \
    STAGE_A(1 - (buf), tn1_, 1);                                                  \
    VMCNT(8);                                                                     \
    BAR; MM(0, af, bv1); BAR;                                                     \
    /* P3: (mq1, kk0) -- reuse bv0 */                                             \
    LDA_F(af, buf, 1, 0);                                                         \
    STAGE_A(buf, tn2_, 0);                                                        \
    BAR; MM(1, af, bv0); BAR;                                                     \
    /* P4: (mq1, kk1) -- reuse bv1 */                                             \
    LDA_F(af, buf, 1, 1);                                                         \
    STAGE_B(buf, tn2_, 0);                                                        \
    VMCNT(6);                                                                     \
    BAR; MM(1, af, bv1); BAR;                                                     \
  } while (0)

  // prologue FIFO: [A0t0, B0t0, B1t0, A1t0, A0t1, B0t1]
  STAGE_A(0, 0, 0); STAGE_B(0, 0, 0);
  STAGE_B(0, 0, 1); STAGE_A(0, 0, 1);
  STAGE_A(1, 1, 0); STAGE_B(1, 1, 0);
  VMCNT(6);                      // confirms A0,B0,B1 of t0 for P1's reads
  BAR;

  for (int j = 0; j < NT_/2; ++j) {
    TILE(0, 2*j);
    TILE(1, 2*j + 1);
  }

  if (!vz) {
    // swapped epilogue: row = m-dim (lo fixed), 4 consecutive cols -> 8B stores
#pragma unroll
    for (int m = 0; m < 8; ++m) {
      int row = mbase + wr*128 + m*16 + lo;
#pragma unroll
      for (int n = 0; n < 4; ++n) {
        int colb = nbase + wc*64 + n*16 + hi*4;
        float4 b4 = *(const float4*)&bias[colb];
        u32 d01 = (u32)f2bf((acc[m][n][0] + b4.x) * osc)
                | ((u32)f2bf((acc[m][n][1] + b4.y) * osc) << 16);
        u32 d23 = (u32)f2bf((acc[m][n][2] + b4.z) * osc)
                | ((u32)f2bf((acc[m][n][3] + b4.w) * osc) << 16);
        *(uint2*)&C[(size_t)row*D_ + colb] = make_uint2(d01, d23);
      }
    }
  } else {
    // V: unswapped -> lane has 4 consecutive s-values at fixed feature.
    // Write transposed directly: Vt[(b*1024 + feat)*S + s] (feat = h*64+dk).
#pragma unroll
    for (int m = 0; m < 8; ++m) {
      int s0 = mbase + wr*128 + m*16 + hi*4;
      int bb = s0 >> 11, sl = s0 & (S_ - 1);
#pragma unroll
      for (int n = 0; n < 4; ++n) {
        int feat = nbase + wc*64 + n*16 + lo;
        float bvv = bias[feat];
        u32 d01 = (u32)f2bf(acc[m][n][0] + bvv)
                | ((u32)f2bf(acc[m][n][1] + bvv) << 16);
        u32 d23 = (u32)f2bf(acc[m][n][2] + bvv)
                | ((u32)f2bf(acc[m][n][3] + bvv) << 16);
        *(uint2*)&C[((size_t)(bb*1024 + feat))*S_ + sl] = make_uint2(d01, d23);
      }
    }
  }
#undef TILE
#undef MM
#undef LDA_F
#undef LDB_F
#undef STAGE_A
#undef STAGE_B
#undef BAR
}

// ---------------- GEMM 64x128 tile (out-projection, fp32 out, swapped) ----------------
__global__ __launch_bounds__(256) void gemm_bt64(
    const u16* __restrict__ A, const u16* __restrict__ W,
    const float* __restrict__ bias, float* __restrict__ C,
    int M, int N, int K) {
  __shared__ u16 As[64*32];
  __shared__ u16 Bs[128*32];
  const int tid = threadIdx.x;
  const int wave = tid >> 6, lane = tid & 63;
  const int lo = lane & 15, hi = lane >> 4;
  const int mbase = blockIdx.y * 64, nbase = blockIdx.x * 128;

  f32x4 acc[4][2] = {};

  for (int k0 = 0; k0 < K; k0 += 32) {
    {
      int row = tid >> 2;
      int col = (tid & 3) * 8;
      gload_lds16(&A[(size_t)(mbase + row)*K + k0 + col], &As[row*32 + col]);
#pragma unroll
      for (int i = 0; i < 2; ++i)
        gload_lds16(&W[(size_t)(nbase + i*64 + row)*K + k0 + col], &Bs[(i*64 + row)*32 + col]);
    }
    __syncthreads();
    bf16x8 af[4], bfr[2];
#pragma unroll
    for (int m = 0; m < 4; ++m)
      af[m] = *(const bf16x8*)&As[(m*16 + lo)*32 + hi*8];
#pragma unroll
    for (int n = 0; n < 2; ++n)
      bfr[n] = *(const bf16x8*)&Bs[(wave*32 + n*16 + lo)*32 + hi*8];
#pragma unroll
    for (int m = 0; m < 4; ++m)
#pragma unroll
      for (int n = 0; n < 2; ++n)
        acc[m][n] = mfma16(bfr[n], af[m], acc[m][n]);   // swapped: rows=n, cols=m
    __syncthreads();
  }

  // swapped epilogue: per lane row = mbase+m*16+lo, 4 consecutive cols -> float4
#pragma unroll
  for (int m = 0; m < 4; ++m) {
    int row = mbase + m*16 + lo;
#pragma unroll
    for (int n = 0; n < 2; ++n) {
      int colb = nbase + wave*32 + n*16 + hi*4;
      float4 b4 = *(const float4*)&bias[colb];
      float4 ov = make_float4(acc[m][n][0] + b4.x, acc[m][n][1] + b4.y,
                              acc[m][n][2] + b4.z, acc[m][n][3] + b4.w);
      *(float4*)&C[(size_t)row*N + colb] = ov;
    }
  }
}

// ---------------- causal flash attention, QBLK=128 (32 q-rows/wave) ----------------
// Grid 512 (16 q-blocks x 32 bh), longest-first, XCD-clustered bh.
// 2 q-groups per wave: K/V LDS fragments read ONCE per (kk,n) and fed to both
// groups' MFMA -> 20 ds_read per 32 MFMA (was 18 per 16). Staging, barriers,
// FETCH all halve per unit work. Direct-to-LDS staging w/ pre-swizzled source,
// double-buffered, 1 barrier/iter. Swapped QK^T (per-lane q), shuffle-free
// common-path softmax, defer-max, swapped PV, packed 8B output stores.
__global__ __launch_bounds__(256) void attn_kernel(
    const u16* __restrict__ Q, const u16* __restrict__ K, const u16* __restrict__ Vt,
    u16* __restrict__ AO) {
  const int blk = blockIdx.x;
  const int xcd = blk & 7, slot = blk >> 3;   // slot 0..63
  const int bh = xcd + 8*(slot & 3);          // 4 bh per XCD
  const int qt = 15 - (slot >> 2);            // longest-first (128-row q blocks)
  const int b = bh >> 4, h = bh & 15;
  const int tid = threadIdx.x, w = tid >> 6, lane = tid & 63;
  const int lo = lane & 15, hi = lane >> 4;
  const int nkt = 2*qt + 2;                   // kv tiles of 64

  __shared__ u16 Kl[2][64*64];
  __shared__ u16 Vl[2][64*64];
  __shared__ u16 Pl[4][32*72];

  const int r8 = lane >> 3;                   // 0..7 == row&7
  const int rloc = w*8 + r8;                  // 0..31
  const int xorcol = ((lane & 7) ^ r8) * 8;   // pre-swizzled global column
  const size_t kbase = (size_t)b*S_*D_ + (size_t)h*DK_;
  const size_t vbase = (size_t)bh*DK_*S_;
  const size_t koff0 = kbase + (size_t)rloc*D_ + xorcol;
  const size_t koff1 = kbase + (size_t)(32 + rloc)*D_ + xorcol;
  const size_t voff0 = vbase + (size_t)rloc*S_ + xorcol;
  const size_t voff1 = vbase + (size_t)(32 + rloc)*S_ + xorcol;
  const int ldsoff = rloc*64 + (lane & 7)*8;  // linear: wave base + lane*16B

  int qr[2];
  bf16x8 qf[2][2];
#pragma unroll
  for (int g = 0; g < 2; ++g) {
    qr[g] = qt*128 + w*32 + g*16 + lo;
#pragma unroll
    for (int kk = 0; kk < 2; ++kk)
      qf[g][kk] = *(const bf16x8*)&Q[(size_t)(b*S_ + qr[g])*D_ + h*DK_ + kk*32 + hi*8];
  }

  f32x4 o[2][4] = {};
  float mr[2] = {-INFINITY, -INFINITY}, lr[2] = {0.f, 0.f};

  gload_lds16(&K[koff0], &Kl[0][ldsoff]);
  gload_lds16(&K[koff1], &Kl[0][2048 + ldsoff]);
  gload_lds16(&Vt[voff0], &Vl[0][ldsoff]);
  gload_lds16(&Vt[voff1], &Vl[0][2048 + ldsoff]);

  const int wave_qmax = qt*128 + w*32 + 31;

  for (int kt = 0; kt < nkt; ++kt) {
    const int cur = kt & 1;
    __syncthreads();   // tile kt resident; buf cur^1 free
    if (kt + 1 < nkt) {
      const size_t kadd = (size_t)(kt + 1)*64*D_;
      const int vadd = (kt + 1)*64;
      gload_lds16(&K[koff0 + kadd], &Kl[cur ^ 1][ldsoff]);
      gload_lds16(&K[koff1 + kadd], &Kl[cur ^ 1][2048 + ldsoff]);
      gload_lds16(&Vt[voff0 + vadd], &Vl[cur ^ 1][ldsoff]);
      gload_lds16(&Vt[voff1 + vadd], &Vl[cur ^ 1][2048 + ldsoff]);
    }

    if (kt*64 > wave_qmax) continue;   // fully-masked tile for this wave (uniform)

    // S^T = K Q^T per group: s[g][n][j] = score(q=qr[g], kv=kt*64 + n*16+hi*4+j)
    f32x4 s[2][4] = {};
#pragma unroll
    for (int kk = 0; kk < 2; ++kk) {
#pragma unroll
      for (int n = 0; n < 4; ++n) {
        int row = n*16 + lo;
        bf16x8 kf = *(const bf16x8*)&Kl[cur][row*64 + (((kk*4 + hi) ^ (row & 7)) * 8)];
        s[0][n] = mfma16(kf, qf[0][kk], s[0][n]);
        s[1][n] = mfma16(kf, qf[1][kk], s[1][n]);
      }
    }

    if (kt >= 2*qt) {  // diagonal region: causal mask
#pragma unroll
      for (int g = 0; g < 2; ++g)
#pragma unroll
        for (int n = 0; n < 4; ++n)
#pragma unroll
          for (int j = 0; j < 4; ++j)
            if (kt*64 + n*16 + hi*4 + j > qr[g]) s[g][n][j] = -INFINITY;
    }

    float pm[2] = {-INFINITY, -INFINITY};
#pragma unroll
    for (int g = 0; g < 2; ++g)
#pragma unroll
      for (int n = 0; n < 4; ++n)
#pragma unroll
        for (int j = 0; j < 4; ++j) pm[g] = fmaxf(pm[g], s[g][n][j]);

    if (!__all(fmaxf(pm[0] - mr[0], pm[1] - mr[1]) <= 11.0f)) {  // defer-max
#pragma unroll
      for (int g = 0; g < 2; ++g) {
        float t = fmaxf(pm[g], __shfl_xor(pm[g], 16));
        t = fmaxf(t, __shfl_xor(t, 32));
        float mn = fmaxf(mr[g], t);
        float corr = __builtin_amdgcn_exp2f(mr[g] - mn);
        mr[g] = mn;
        lr[g] *= corr;
#pragma unroll
        for (int n = 0; n < 4; ++n)
#pragma unroll
          for (int j = 0; j < 4; ++j) o[g][n][j] *= corr;
      }
    }

#pragma unroll
    for (int g = 0; g < 2; ++g)
#pragma unroll
      for (int n = 0; n < 4; ++n) {
        float p0 = __builtin_amdgcn_exp2f(s[g][n][0] - mr[g]);
        float p1 = __builtin_amdgcn_exp2f(s[g][n][1] - mr[g]);
        float p2 = __builtin_amdgcn_exp2f(s[g][n][2] - mr[g]);
        float p3 = __builtin_amdgcn_exp2f(s[g][n][3] - mr[g]);
        lr[g] += (p0 + p1) + (p2 + p3);
        u32 d01 = (u32)f2bfr(p0) | ((u32)f2bfr(p1) << 16);
        u32 d23 = (u32)f2bfr(p2) | ((u32)f2bfr(p3) << 16);
        *(uint2*)&Pl[w][(g*16 + lo)*72 + n*16 + hi*4] = make_uint2(d01, d23);
      }

    // O^T += V P^T per group; vf read once, used by both groups
#pragma unroll
    for (int kk = 0; kk < 2; ++kk) {
      bf16x8 pf0 = *(const bf16x8*)&Pl[w][lo*72 + kk*32 + hi*8];
      bf16x8 pf1 = *(const bf16x8*)&Pl[w][(16 + lo)*72 + kk*32 + hi*8];
#pragma unroll
      for (int n = 0; n < 4; ++n) {
        int row = n*16 + lo;
        bf16x8 vf = *(const bf16x8*)&Vl[cur][row*64 + (((kk*4 + hi) ^ (row & 7)) * 8)];
        o[0][n] = mfma16(vf, pf0, o[0][n]);
        o[1][n] = mfma16(vf, pf1, o[1][n]);
      }
    }
  }

#pragma unroll
  for (int g = 0; g < 2; ++g) {
    lr[g] += __shfl_xor(lr[g], 16);
    lr[g] += __shfl_xor(lr[g], 32);
    const float rinv = __builtin_amdgcn_rcpf(lr[g]);
    const size_t obase = (size_t)(b*S_ + qr[g])*D_ + h*DK_;
#pragma unroll
    for (int n = 0; n < 4; ++n) {
      u32 d01 = (u32)f2bf(o[g][n][0] * rinv) | ((u32)f2bf(o[g][n][1] * rinv) << 16);
      u32 d23 = (u32)f2bf(o[g][n][2] * rinv) | ((u32)f2bf(o[g][n][3] * rinv) << 16);
      *(uint2*)&AO[obase + n*16 + hi*4] = make_uint2(d01, d23);
    }
  }
}

extern "C" void kernel_launch(void* const* d_in, const int* in_sizes, int n_in,
                              void* d_out, int out_size, void* d_ws, size_t ws_size,
                              hipStream_t stream) {
  const float* x  = (const float*)d_in[0];
  const float* Wq = (const float*)d_in[1];
  const float* bq = (const float*)d_in[2];
  const float* Wk = (const float*)d_in[3];
  const float* bk = (const float*)d_in[4];
  const float* Wv = (const float*)d_in[5];
  const float* bv = (const float*)d_in[6];
  const float* Wo = (const float*)d_in[7];
  const float* bo = (const float*)d_in[8];

  char* ws = (char*)d_ws;
  const size_t MB = 1048576;
  u16* xb  = (u16*)(ws + 0);        // 8 MiB (dead after QKV gemm)
  u16* Wqb = (u16*)(ws + 8*MB);     // 2 MiB each
  u16* Wkb = (u16*)(ws + 10*MB);
  u16* Wvb = (u16*)(ws + 12*MB);
  u16* Wob = (u16*)(ws + 14*MB);
  u16* Qb  = (u16*)(ws + 16*MB);    // 8 MiB
  u16* Kb  = (u16*)(ws + 24*MB);    // 8 MiB
  u16* Vtb = (u16*)(ws + 32*MB);    // 8 MiB (written transposed by gemm z==2)
  u16* AOb = (u16*)(ws + 0);        // reuses xb slot

  f2bf_kernel<<<4096, 256, 0, stream>>>(x, xb, (M_*D_)/4);
  f2bf4_kernel<<<dim3(1024, 4), 256, 0, stream>>>(Wq, Wk, Wv, Wo,
                                                  Wqb, Wkb, Wvb, Wob, (D_*D_)/4);

  gemm_qkv_8ph<<<192, 512, 0, stream>>>(xb, Wqb, Wkb, Wvb, bq, bk, bv, Qb, Kb, Vtb);

  attn_kernel<<<512, 256, 0, stream>>>(Qb, Kb, Vtb, AOb);

  gemm_bt64<<<dim3(8, 64), 256, 0, stream>>>(AOb, Wob, bo, (float*)d_out, M_, D_, D_);
}

// Round 10
// 119.704 us; speedup vs baseline: 1.0948x; 1.0948x over previous
//
#include <hip/hip_runtime.h>
#include <stdint.h>
#include <math.h>

#define B_ 2
#define S_ 2048
#define D_ 1024
#define H_ 16
#define DK_ 64
#define M_ (B_*S_)   // 4096
#define NT_ 16       // K tiles of 64 in D_=1024

typedef unsigned short u16;
typedef unsigned int u32;
typedef __attribute__((ext_vector_type(8))) __bf16 bf16x8;
typedef __attribute__((ext_vector_type(4))) float f32x4;

#define AS1 __attribute__((address_space(1)))
#define AS3 __attribute__((address_space(3)))

__device__ __forceinline__ u16 f2bf(float f) {
  u32 u = __float_as_uint(f);
  return (u16)((u + 0x7fffu + ((u >> 16) & 1u)) >> 16);  // RNE
}

// pack 2 fp32 -> 2 bf16 in one VALU op (compiler won't derive from bit-RNE)
__device__ __forceinline__ u32 cvtpk(float a, float b) {
  u32 r;
  asm("v_cvt_pk_bf16_f32 %0, %1, %2" : "=v"(r) : "v"(a), "v"(b));
  return r;
}

__device__ __forceinline__ void gload_lds16(const void* g, void* lds) {
  __builtin_amdgcn_global_load_lds((const AS1 u32*)g,
                                   (AS3 u32*)(u32)(uintptr_t)lds, 16, 0, 0);
}

__device__ __forceinline__ f32x4 mfma16(bf16x8 a, bf16x8 b, f32x4 c) {
  return __builtin_amdgcn_mfma_f32_16x16x32_bf16(a, b, c, 0, 0, 0);
}

#define VMCNT_(n) asm volatile("s_waitcnt vmcnt(" #n ")" ::: "memory")
#define VMCNT(n) VMCNT_(n)

// ---------------- fp32 -> bf16 convert (vectorized) ----------------
__global__ __launch_bounds__(256) void f2bf_kernel(const float* __restrict__ in,
                                                   u16* __restrict__ out, int n4) {
  int i = blockIdx.x * 256 + threadIdx.x;
  if (i >= n4) return;
  float4 v = ((const float4*)in)[i];
  ((uint2*)out)[i] = make_uint2((u32)f2bf(v.x) | ((u32)f2bf(v.y) << 16),
                                (u32)f2bf(v.z) | ((u32)f2bf(v.w) << 16));
}

// fused 4-weight convert (blockIdx.y selects matrix)
__global__ __launch_bounds__(256) void f2bf4_kernel(
    const float* __restrict__ W0, const float* __restrict__ W1,
    const float* __restrict__ W2, const float* __restrict__ W3,
    u16* __restrict__ o0, u16* __restrict__ o1, u16* __restrict__ o2, u16* __restrict__ o3,
    int n4) {
  const float* src; u16* dst;
  switch (blockIdx.y) {
    case 0: src = W0; dst = o0; break;
    case 1: src = W1; dst = o1; break;
    case 2: src = W2; dst = o2; break;
    default: src = W3; dst = o3; break;
  }
  int i = blockIdx.x * 256 + threadIdx.x;
  if (i >= n4) return;
  float4 v = ((const float4*)src)[i];
  ((uint2*)dst)[i] = make_uint2((u32)f2bf(v.x) | ((u32)f2bf(v.y) << 16),
                                (u32)f2bf(v.z) | ((u32)f2bf(v.w) << 16));
}

// =============== QKV GEMM: 8-phase, operand-reuse, fused V-transpose ===============
// Operand-reuse kk-decomposition, counted vmcnt, dead-region staging, pre-swizzled
// source. Q/K (z<2): swapped mfma(bv,af) -> packed 8B row-major stores. V (z==2):
// unswapped -> lane holds 4 consecutive s-values -> writes Vt[b,h,dk,s] directly
// (transpose fused). Epilogue packing via v_cvt_pk_bf16_f32.
__global__ __launch_bounds__(512, 2) void gemm_qkv_8ph(
    const u16* __restrict__ A,
    const u16* __restrict__ W0, const u16* __restrict__ W1, const u16* __restrict__ W2,
    const float* __restrict__ b0, const float* __restrict__ b1, const float* __restrict__ b2,
    u16* __restrict__ C0, u16* __restrict__ C1, u16* __restrict__ C2) {
  // grid = 192: xcd-major decode, my pairs per XCD for A-panel L2 locality
  const int id = blockIdx.x;
  const int xcd = id & 7, k = id >> 3;        // k 0..23
  const int my = xcd*2 + (k & 1);             // 0..15
  const int rest = k >> 1;                    // 0..11
  const int z = rest >> 2, nx = rest & 3;     // matrix, n-tile

  const u16* W = (z == 0) ? W0 : (z == 1) ? W1 : W2;
  const float* bias = (z == 0) ? b0 : (z == 1) ? b1 : b2;
  u16* C = (z == 0) ? C0 : (z == 1) ? C1 : C2;
  const float osc = (z == 0) ? 0.18033688f : 1.0f;   // Q pre-scaled: 0.125*log2(e)
  const bool vz = (z == 2);
  const int mbase = my*256, nbase = nx*256;

  __shared__ u16 LA[2][256*64];
  __shared__ u16 LB[2][256*64];

  const int tid = threadIdx.x;              // 0..511
  const int w = tid >> 6, lane = tid & 63;
  const int lo = lane & 15, hi = lane >> 4;
  const int wr = w >> 2, wc = w & 3;

  const int sr = tid >> 3;
  const int sc = tid & 7;
  const int sx = (sc ^ (sr & 7)) * 8;

#define STAGE_A(buf, t, h) do {                                                   \
    int gr_ = sr + (h)*64;                                                        \
    size_t g_ = (size_t)(mbase + gr_)*D_ + (size_t)(t)*64 + sx;                   \
    gload_lds16(&A[g_],            &LA[buf][gr_*64 + sc*8]);                      \
    gload_lds16(&A[g_ + 128*D_],   &LA[buf][(gr_ + 128)*64 + sc*8]);              \
  } while (0)

#define STAGE_B(buf, t, h) do {                                                   \
    int gr_ = (sr & 31) + (h)*32 + (sr >> 5)*64;                                  \
    size_t g_ = (size_t)(nbase + gr_)*D_ + (size_t)(t)*64 + sx;                   \
    gload_lds16(&W[g_],            &LB[buf][gr_*64 + sc*8]);                      \
    gload_lds16(&W[g_ + 128*D_],   &LB[buf][(gr_ + 128)*64 + sc*8]);              \
  } while (0)

#define LDA_F(dst, buf, mq, kk) do {                                              \
    _Pragma("unroll")                                                             \
    for (int m_ = 0; m_ < 4; ++m_) {                                              \
      int R_ = wr*128 + (mq)*64 + m_*16 + lo;                                     \
      dst[m_] = *(const bf16x8*)&LA[buf][R_*64 + ((((kk)*4 + hi) ^ (R_ & 7))*8)]; \
    }                                                                             \
  } while (0)

#define LDB_F(dst, buf, kk) do {                                                  \
    _Pragma("unroll")                                                             \
    for (int q_ = 0; q_ < 2; ++q_)                                                \
      _Pragma("unroll")                                                           \
      for (int n_ = 0; n_ < 2; ++n_) {                                            \
        int R_ = wc*64 + q_*32 + n_*16 + lo;                                      \
        dst[q_][n_] =                                                             \
            *(const bf16x8*)&LB[buf][R_*64 + ((((kk)*4 + hi) ^ (R_ & 7))*8)];     \
      }                                                                           \
  } while (0)

#define MM(mq, af_, bv_) do {                                                     \
    __builtin_amdgcn_s_setprio(1);                                                \
    if (vz) {                                                                     \
      _Pragma("unroll")                                                           \
      for (int m_ = 0; m_ < 4; ++m_)                                              \
        _Pragma("unroll")                                                         \
        for (int q_ = 0; q_ < 2; ++q_)                                            \
          _Pragma("unroll")                                                       \
          for (int n_ = 0; n_ < 2; ++n_)                                          \
            acc[(mq)*4 + m_][q_*2 + n_] =                                         \
                mfma16(af_[m_], bv_[q_][n_], acc[(mq)*4 + m_][q_*2 + n_]);        \
    } else {                                                                      \
      _Pragma("unroll")                                                           \
      for (int m_ = 0; m_ < 4; ++m_)                                              \
        _Pragma("unroll")                                                         \
        for (int q_ = 0; q_ < 2; ++q_)                                            \
          _Pragma("unroll")                                                       \
          for (int n_ = 0; n_ < 2; ++n_)                                          \
            acc[(mq)*4 + m_][q_*2 + n_] =                                         \
                mfma16(bv_[q_][n_], af_[m_], acc[(mq)*4 + m_][q_*2 + n_]);        \
    }                                                                             \
    __builtin_amdgcn_s_setprio(0);                                                \
  } while (0)

#define BAR __builtin_amdgcn_s_barrier()

  f32x4 acc[8][4] = {};

#define TILE(buf, t) do {                                                         \
    const int tn1_ = ((t) + 1 < NT_) ? (t) + 1 : NT_ - 1;                         \
    const int tn2_ = ((t) + 2 < NT_) ? (t) + 2 : NT_ - 1;                         \
    bf16x8 af[4], bv0[2][2], bv1[2][2];                                           \
    LDA_F(af, buf, 0, 0); LDB_F(bv0, buf, 0);                                     \
    STAGE_B(1 - (buf), tn1_, 1);                                                  \
    BAR; MM(0, af, bv0); BAR;                                                     \
    LDA_F(af, buf, 0, 1); LDB_F(bv1, buf, 1);                                     \
    STAGE_A(1 - (buf), tn1_, 1);                                                  \
    VMCNT(8);                                                                     \
    BAR; MM(0, af, bv1); BAR;                                                     \
    LDA_F(af, buf, 1, 0);                                                         \
    STAGE_A(buf, tn2_, 0);                                                        \
    BAR; MM(1, af, bv0); BAR;                                                     \
    LDA_F(af, buf, 1, 1);                                                         \
    STAGE_B(buf, tn2_, 0);                                                        \
    VMCNT(6);                                                                     \
    BAR; MM(1, af, bv1); BAR;                                                     \
  } while (0)

  // prologue FIFO: [A0t0, B0t0, B1t0, A1t0, A0t1, B0t1]
  STAGE_A(0, 0, 0); STAGE_B(0, 0, 0);
  STAGE_B(0, 0, 1); STAGE_A(0, 0, 1);
  STAGE_A(1, 1, 0); STAGE_B(1, 1, 0);
  VMCNT(6);
  BAR;

  for (int j = 0; j < NT_/2; ++j) {
    TILE(0, 2*j);
    TILE(1, 2*j + 1);
  }

  if (!vz) {
#pragma unroll
    for (int m = 0; m < 8; ++m) {
      int row = mbase + wr*128 + m*16 + lo;
#pragma unroll
      for (int n = 0; n < 4; ++n) {
        int colb = nbase + wc*64 + n*16 + hi*4;
        float4 b4 = *(const float4*)&bias[colb];
        *(uint2*)&C[(size_t)row*D_ + colb] = make_uint2(
            cvtpk((acc[m][n][0] + b4.x) * osc, (acc[m][n][1] + b4.y) * osc),
            cvtpk((acc[m][n][2] + b4.z) * osc, (acc[m][n][3] + b4.w) * osc));
      }
    }
  } else {
    // V: lane has 4 consecutive s-values at fixed feature -> Vt[(b*1024+feat)*S + s]
#pragma unroll
    for (int m = 0; m < 8; ++m) {
      int s0 = mbase + wr*128 + m*16 + hi*4;
      int bb = s0 >> 11, sl = s0 & (S_ - 1);
#pragma unroll
      for (int n = 0; n < 4; ++n) {
        int feat = nbase + wc*64 + n*16 + lo;
        float bvv = bias[feat];
        *(uint2*)&C[((size_t)(bb*1024 + feat))*S_ + sl] = make_uint2(
            cvtpk(acc[m][n][0] + bvv, acc[m][n][1] + bvv),
            cvtpk(acc[m][n][2] + bvv, acc[m][n][3] + bvv));
      }
    }
  }
#undef TILE
#undef MM
#undef LDA_F
#undef LDB_F
#undef STAGE_A
#undef STAGE_B
#undef BAR
}

// ---------------- GEMM 64x128 tile (out-projection, fp32 out, swapped) ----------------
__global__ __launch_bounds__(256) void gemm_bt64(
    const u16* __restrict__ A, const u16* __restrict__ W,
    const float* __restrict__ bias, float* __restrict__ C,
    int M, int N, int K) {
  __shared__ u16 As[64*32];
  __shared__ u16 Bs[128*32];
  const int tid = threadIdx.x;
  const int wave = tid >> 6, lane = tid & 63;
  const int lo = lane & 15, hi = lane >> 4;
  const int mbase = blockIdx.y * 64, nbase = blockIdx.x * 128;

  f32x4 acc[4][2] = {};

  for (int k0 = 0; k0 < K; k0 += 32) {
    {
      int row = tid >> 2;
      int col = (tid & 3) * 8;
      gload_lds16(&A[(size_t)(mbase + row)*K + k0 + col], &As[row*32 + col]);
#pragma unroll
      for (int i = 0; i < 2; ++i)
        gload_lds16(&W[(size_t)(nbase + i*64 + row)*K + k0 + col], &Bs[(i*64 + row)*32 + col]);
    }
    __syncthreads();
    bf16x8 af[4], bfr[2];
#pragma unroll
    for (int m = 0; m < 4; ++m)
      af[m] = *(const bf16x8*)&As[(m*16 + lo)*32 + hi*8];
#pragma unroll
    for (int n = 0; n < 2; ++n)
      bfr[n] = *(const bf16x8*)&Bs[(wave*32 + n*16 + lo)*32 + hi*8];
#pragma unroll
    for (int m = 0; m < 4; ++m)
#pragma unroll
      for (int n = 0; n < 2; ++n)
        acc[m][n] = mfma16(bfr[n], af[m], acc[m][n]);   // swapped: rows=n, cols=m
    __syncthreads();
  }

#pragma unroll
  for (int m = 0; m < 4; ++m) {
    int row = mbase + m*16 + lo;
#pragma unroll
    for (int n = 0; n < 2; ++n) {
      int colb = nbase + wave*32 + n*16 + hi*4;
      float4 b4 = *(const float4*)&bias[colb];
      float4 ov = make_float4(acc[m][n][0] + b4.x, acc[m][n][1] + b4.y,
                              acc[m][n][2] + b4.z, acc[m][n][3] + b4.w);
      *(float4*)&C[(size_t)row*N + colb] = ov;
    }
  }
}

// ---------------- causal flash attention (QBLK=64, swapped PV, cvt_pk) ----------------
// Grid 1024 (1 q-tile/block, longest-first, XCD-clustered bh). Direct-to-LDS
// staging w/ pre-swizzled source, double-buffered, 1 barrier/iter. Swapped QK^T
// (per-lane q = lo) -> shuffle-free common path; defer-max; swapped PV -> lane-
// scalar corr and 1/l; P and AO packed via v_cvt_pk_bf16_f32.
__global__ __launch_bounds__(256) void attn_kernel(
    const u16* __restrict__ Q, const u16* __restrict__ K, const u16* __restrict__ Vt,
    u16* __restrict__ AO) {
  const int blk = blockIdx.x;
  const int xcd = blk & 7, slot = blk >> 3;   // slot 0..127
  const int bh = xcd + 8*(slot & 3);          // 4 bh per XCD
  const int qt = 31 - (slot >> 2);            // longest-first
  const int b = bh >> 4, h = bh & 15;
  const int tid = threadIdx.x, w = tid >> 6, lane = tid & 63;
  const int lo = lane & 15, hi = lane >> 4;

  __shared__ u16 Kl[2][64*64];
  __shared__ u16 Vl[2][64*64];
  __shared__ u16 Pl[4][16*72];

  const int r8 = lane >> 3;
  const int rloc = w*8 + r8;
  const int xorcol = ((lane & 7) ^ r8) * 8;
  const size_t kbase = (size_t)b*S_*D_ + (size_t)h*DK_;
  const size_t vbase = (size_t)bh*DK_*S_;
  const size_t koff0 = kbase + (size_t)rloc*D_ + xorcol;
  const size_t koff1 = kbase + (size_t)(32 + rloc)*D_ + xorcol;
  const size_t voff0 = vbase + (size_t)rloc*S_ + xorcol;
  const size_t voff1 = vbase + (size_t)(32 + rloc)*S_ + xorcol;
  const int ldsoff = rloc*64 + (lane & 7)*8;

  const int qrow = qt*64 + w*16 + lo;
  bf16x8 qf[2];
#pragma unroll
  for (int kk = 0; kk < 2; ++kk)
    qf[kk] = *(const bf16x8*)&Q[(size_t)(b*S_ + qrow)*D_ + h*DK_ + kk*32 + hi*8];

  f32x4 o[4] = {};
  float mr = -INFINITY, lr = 0.f;

  gload_lds16(&K[koff0], &Kl[0][ldsoff]);
  gload_lds16(&K[koff1], &Kl[0][2048 + ldsoff]);
  gload_lds16(&Vt[voff0], &Vl[0][ldsoff]);
  gload_lds16(&Vt[voff1], &Vl[0][2048 + ldsoff]);

  for (int kt = 0; kt <= qt; ++kt) {
    const int cur = kt & 1;
    __syncthreads();   // tile kt resident; buf cur^1 free
    if (kt < qt) {
      const size_t kadd = (size_t)(kt + 1)*64*D_;
      const int vadd = (kt + 1)*64;
      gload_lds16(&K[koff0 + kadd], &Kl[cur ^ 1][ldsoff]);
      gload_lds16(&K[koff1 + kadd], &Kl[cur ^ 1][2048 + ldsoff]);
      gload_lds16(&Vt[voff0 + vadd], &Vl[cur ^ 1][ldsoff]);
      gload_lds16(&Vt[voff1 + vadd], &Vl[cur ^ 1][2048 + ldsoff]);
    }

    // S^T = K Q^T : lane holds s[n][j] = score(q=lo, kv=n*16+hi*4+j)
    f32x4 s[4] = {};
#pragma unroll
    for (int kk = 0; kk < 2; ++kk) {
#pragma unroll
      for (int n = 0; n < 4; ++n) {
        int row = n*16 + lo;
        bf16x8 kf = *(const bf16x8*)&Kl[cur][row*64 + (((kk*4 + hi) ^ (row & 7)) * 8)];
        s[n] = mfma16(kf, qf[kk], s[n]);
      }
    }

    if (kt == qt) {  // causal mask on diagonal tile
      const int ql = w*16 + lo;
#pragma unroll
      for (int n = 0; n < 4; ++n)
#pragma unroll
        for (int j = 0; j < 4; ++j)
          if (n*16 + hi*4 + j > ql) s[n][j] = -INFINITY;
    }

    float pm = -INFINITY;
#pragma unroll
    for (int n = 0; n < 4; ++n)
#pragma unroll
      for (int j = 0; j < 4; ++j) pm = fmaxf(pm, s[n][j]);

    if (!__all(pm <= mr + 11.0f)) {   // defer-max: rescale rarely
      pm = fmaxf(pm, __shfl_xor(pm, 16));
      pm = fmaxf(pm, __shfl_xor(pm, 32));
      float mn = fmaxf(mr, pm);
      float corr = __builtin_amdgcn_exp2f(mr - mn);
      mr = mn;
      lr *= corr;
#pragma unroll
      for (int n = 0; n < 4; ++n)
#pragma unroll
        for (int j = 0; j < 4; ++j) o[n][j] *= corr;
    }

#pragma unroll
    for (int n = 0; n < 4; ++n) {
      float p0 = __builtin_amdgcn_exp2f(s[n][0] - mr);
      float p1 = __builtin_amdgcn_exp2f(s[n][1] - mr);
      float p2 = __builtin_amdgcn_exp2f(s[n][2] - mr);
      float p3 = __builtin_amdgcn_exp2f(s[n][3] - mr);
      lr += (p0 + p1) + (p2 + p3);
      *(uint2*)&Pl[w][lo*72 + n*16 + hi*4] =
          make_uint2(cvtpk(p0, p1), cvtpk(p2, p3));
    }

    // O^T += V P^T (swapped): o[n] rows = dk, cols = q (lo)
#pragma unroll
    for (int kk = 0; kk < 2; ++kk) {
      bf16x8 pf = *(const bf16x8*)&Pl[w][lo*72 + kk*32 + hi*8];
#pragma unroll
      for (int n = 0; n < 4; ++n) {
        int row = n*16 + lo;
        bf16x8 vf = *(const bf16x8*)&Vl[cur][row*64 + (((kk*4 + hi) ^ (row & 7)) * 8)];
        o[n] = mfma16(vf, pf, o[n]);
      }
    }
  }

  lr += __shfl_xor(lr, 16);
  lr += __shfl_xor(lr, 32);
  const float rinv = __builtin_amdgcn_rcpf(lr);
  const size_t obase = (size_t)(b*S_ + qrow)*D_ + h*DK_;
#pragma unroll
  for (int n = 0; n < 4; ++n) {
    *(uint2*)&AO[obase + n*16 + hi*4] =
        make_uint2(cvtpk(o[n][0] * rinv, o[n][1] * rinv),
                   cvtpk(o[n][2] * rinv, o[n][3] * rinv));
  }
}

extern "C" void kernel_launch(void* const* d_in, const int* in_sizes, int n_in,
                              void* d_out, int out_size, void* d_ws, size_t ws_size,
                              hipStream_t stream) {
  const float* x  = (const float*)d_in[0];
  const float* Wq = (const float*)d_in[1];
  const float* bq = (const float*)d_in[2];
  const float* Wk = (const float*)d_in[3];
  const float* bk = (const float*)d_in[4];
  const float* Wv = (const float*)d_in[5];
  const float* bv = (const float*)d_in[6];
  const float* Wo = (const float*)d_in[7];
  const float* bo = (const float*)d_in[8];

  char* ws = (char*)d_ws;
  const size_t MB = 1048576;
  u16* xb  = (u16*)(ws + 0);        // 8 MiB (dead after QKV gemm)
  u16* Wqb = (u16*)(ws + 8*MB);     // 2 MiB each
  u16* Wkb = (u16*)(ws + 10*MB);
  u16* Wvb = (u16*)(ws + 12*MB);
  u16* Wob = (u16*)(ws + 14*MB);
  u16* Qb  = (u16*)(ws + 16*MB);    // 8 MiB
  u16* Kb  = (u16*)(ws + 24*MB);    // 8 MiB
  u16* Vtb = (u16*)(ws + 32*MB);    // 8 MiB (written transposed by gemm z==2)
  u16* AOb = (u16*)(ws + 0);        // reuses xb slot

  f2bf_kernel<<<4096, 256, 0, stream>>>(x, xb, (M_*D_)/4);
  f2bf4_kernel<<<dim3(1024, 4), 256, 0, stream>>>(Wq, Wk, Wv, Wo,
                                                  Wqb, Wkb, Wvb, Wob, (D_*D_)/4);

  gemm_qkv_8ph<<<192, 512, 0, stream>>>(xb, Wqb, Wkb, Wvb, bq, bk, bv, Qb, Kb, Vtb);

  attn_kernel<<<1024, 256, 0, stream>>>(Qb, Kb, Vtb, AOb);

  gemm_bt64<<<dim3(8, 64), 256, 0, stream>>>(AOb, Wob, bo, (float*)d_out, M_, D_, D_);
}

// Round 11
// 111.209 us; speedup vs baseline: 1.1784x; 1.0764x over previous
//
#include <hip/hip_runtime.h>
#include <stdint.h>
#include <math.h>

#define B_ 2
#define S_ 2048
#define D_ 1024
#define H_ 16
#define DK_ 64
#define M_ (B_*S_)   // 4096
#define NT_ 16       // K tiles of 64 in D_=1024

typedef unsigned short u16;
typedef unsigned int u32;
typedef __attribute__((ext_vector_type(8))) __bf16 bf16x8;
typedef __attribute__((ext_vector_type(4))) float f32x4;

#define AS1 __attribute__((address_space(1)))
#define AS3 __attribute__((address_space(3)))

__device__ __forceinline__ u16 f2bf(float f) {
  u32 u = __float_as_uint(f);
  return (u16)((u + 0x7fffu + ((u >> 16) & 1u)) >> 16);  // RNE
}

// pack 2 fp32 -> 2 bf16 in one VALU op
__device__ __forceinline__ u32 cvtpk(float a, float b) {
  u32 r;
  asm("v_cvt_pk_bf16_f32 %0, %1, %2" : "=v"(r) : "v"(a), "v"(b));
  return r;
}

__device__ __forceinline__ void gload_lds16(const void* g, void* lds) {
  __builtin_amdgcn_global_load_lds((const AS1 u32*)g,
                                   (AS3 u32*)(u32)(uintptr_t)lds, 16, 0, 0);
}

__device__ __forceinline__ f32x4 mfma16(bf16x8 a, bf16x8 b, f32x4 c) {
  return __builtin_amdgcn_mfma_f32_16x16x32_bf16(a, b, c, 0, 0, 0);
}

#define VMCNT_(n) asm volatile("s_waitcnt vmcnt(" #n ")" ::: "memory")
#define VMCNT(n) VMCNT_(n)

// ---------------- fp32 -> bf16 convert (vectorized) ----------------
__global__ __launch_bounds__(256) void f2bf_kernel(const float* __restrict__ in,
                                                   u16* __restrict__ out, int n4) {
  int i = blockIdx.x * 256 + threadIdx.x;
  if (i >= n4) return;
  float4 v = ((const float4*)in)[i];
  ((uint2*)out)[i] = make_uint2((u32)f2bf(v.x) | ((u32)f2bf(v.y) << 16),
                                (u32)f2bf(v.z) | ((u32)f2bf(v.w) << 16));
}

// fused 4-weight convert (blockIdx.y selects matrix)
__global__ __launch_bounds__(256) void f2bf4_kernel(
    const float* __restrict__ W0, const float* __restrict__ W1,
    const float* __restrict__ W2, const float* __restrict__ W3,
    u16* __restrict__ o0, u16* __restrict__ o1, u16* __restrict__ o2, u16* __restrict__ o3,
    int n4) {
  const float* src; u16* dst;
  switch (blockIdx.y) {
    case 0: src = W0; dst = o0; break;
    case 1: src = W1; dst = o1; break;
    case 2: src = W2; dst = o2; break;
    default: src = W3; dst = o3; break;
  }
  int i = blockIdx.x * 256 + threadIdx.x;
  if (i >= n4) return;
  float4 v = ((const float4*)src)[i];
  ((uint2*)dst)[i] = make_uint2((u32)f2bf(v.x) | ((u32)f2bf(v.y) << 16),
                                (u32)f2bf(v.z) | ((u32)f2bf(v.w) << 16));
}

// =============== QKV GEMM: 8-phase, operand-reuse, uniform swapped-output ===============
// Operand-reuse kk-decomposition, counted vmcnt, dead-region staging, pre-swizzled
// source. ALL z use swapped mfma(bv,af) -> lane holds 4 consecutive output columns
// -> packed coalesced 8B row-major stores (V-transpose fusion reverted: the runtime
// orientation branch bloated the unrolled loop and the Vt scatter was uncoalesced).
__global__ __launch_bounds__(512, 2) void gemm_qkv_8ph(
    const u16* __restrict__ A,
    const u16* __restrict__ W0, const u16* __restrict__ W1, const u16* __restrict__ W2,
    const float* __restrict__ b0, const float* __restrict__ b1, const float* __restrict__ b2,
    u16* __restrict__ C0, u16* __restrict__ C1, u16* __restrict__ C2) {
  // grid = 192: xcd-major decode, my pairs per XCD for A-panel L2 locality
  const int id = blockIdx.x;
  const int xcd = id & 7, k = id >> 3;        // k 0..23
  const int my = xcd*2 + (k & 1);             // 0..15
  const int rest = k >> 1;                    // 0..11
  const int z = rest >> 2, nx = rest & 3;     // matrix, n-tile

  const u16* W = (z == 0) ? W0 : (z == 1) ? W1 : W2;
  const float* bias = (z == 0) ? b0 : (z == 1) ? b1 : b2;
  u16* C = (z == 0) ? C0 : (z == 1) ? C1 : C2;
  const float osc = (z == 0) ? 0.18033688f : 1.0f;   // Q pre-scaled: 0.125*log2(e)
  const int mbase = my*256, nbase = nx*256;

  __shared__ u16 LA[2][256*64];
  __shared__ u16 LB[2][256*64];

  const int tid = threadIdx.x;              // 0..511
  const int w = tid >> 6, lane = tid & 63;
  const int lo = lane & 15, hi = lane >> 4;
  const int wr = w >> 2, wc = w & 3;

  const int sr = tid >> 3;
  const int sc = tid & 7;
  const int sx = (sc ^ (sr & 7)) * 8;

#define STAGE_A(buf, t, h) do {                                                   \
    int gr_ = sr + (h)*64;                                                        \
    size_t g_ = (size_t)(mbase + gr_)*D_ + (size_t)(t)*64 + sx;                   \
    gload_lds16(&A[g_],            &LA[buf][gr_*64 + sc*8]);                      \
    gload_lds16(&A[g_ + 128*D_],   &LA[buf][(gr_ + 128)*64 + sc*8]);              \
  } while (0)

#define STAGE_B(buf, t, h) do {                                                   \
    int gr_ = (sr & 31) + (h)*32 + (sr >> 5)*64;                                  \
    size_t g_ = (size_t)(nbase + gr_)*D_ + (size_t)(t)*64 + sx;                   \
    gload_lds16(&W[g_],            &LB[buf][gr_*64 + sc*8]);                      \
    gload_lds16(&W[g_ + 128*D_],   &LB[buf][(gr_ + 128)*64 + sc*8]);              \
  } while (0)

#define LDA_F(dst, buf, mq, kk) do {                                              \
    _Pragma("unroll")                                                             \
    for (int m_ = 0; m_ < 4; ++m_) {                                              \
      int R_ = wr*128 + (mq)*64 + m_*16 + lo;                                     \
      dst[m_] = *(const bf16x8*)&LA[buf][R_*64 + ((((kk)*4 + hi) ^ (R_ & 7))*8)]; \
    }                                                                             \
  } while (0)

#define LDB_F(dst, buf, kk) do {                                                  \
    _Pragma("unroll")                                                             \
    for (int q_ = 0; q_ < 2; ++q_)                                                \
      _Pragma("unroll")                                                           \
      for (int n_ = 0; n_ < 2; ++n_) {                                            \
        int R_ = wc*64 + q_*32 + n_*16 + lo;                                      \
        dst[q_][n_] =                                                             \
            *(const bf16x8*)&LB[buf][R_*64 + ((((kk)*4 + hi) ^ (R_ & 7))*8)];     \
      }                                                                           \
  } while (0)

  // swapped: mfma(bv, af) -> D rows = n (hi*4+jj), D cols = m (lo)
#define MM(mq, af_, bv_) do {                                                     \
    __builtin_amdgcn_s_setprio(1);                                                \
    _Pragma("unroll")                                                             \
    for (int m_ = 0; m_ < 4; ++m_)                                                \
      _Pragma("unroll")                                                           \
      for (int q_ = 0; q_ < 2; ++q_)                                              \
        _Pragma("unroll")                                                         \
        for (int n_ = 0; n_ < 2; ++n_)                                            \
          acc[(mq)*4 + m_][q_*2 + n_] =                                           \
              mfma16(bv_[q_][n_], af_[m_], acc[(mq)*4 + m_][q_*2 + n_]);          \
    __builtin_amdgcn_s_setprio(0);                                                \
  } while (0)

#define BAR __builtin_amdgcn_s_barrier()

  f32x4 acc[8][4] = {};

#define TILE(buf, t) do {                                                         \
    const int tn1_ = ((t) + 1 < NT_) ? (t) + 1 : NT_ - 1;                         \
    const int tn2_ = ((t) + 2 < NT_) ? (t) + 2 : NT_ - 1;                         \
    bf16x8 af[4], bv0[2][2], bv1[2][2];                                           \
    LDA_F(af, buf, 0, 0); LDB_F(bv0, buf, 0);                                     \
    STAGE_B(1 - (buf), tn1_, 1);                                                  \
    BAR; MM(0, af, bv0); BAR;                                                     \
    LDA_F(af, buf, 0, 1); LDB_F(bv1, buf, 1);                                     \
    STAGE_A(1 - (buf), tn1_, 1);                                                  \
    VMCNT(8);                                                                     \
    BAR; MM(0, af, bv1); BAR;                                                     \
    LDA_F(af, buf, 1, 0);                                                         \
    STAGE_A(buf, tn2_, 0);                                                        \
    BAR; MM(1, af, bv0); BAR;                                                     \
    LDA_F(af, buf, 1, 1);                                                         \
    STAGE_B(buf, tn2_, 0);                                                        \
    VMCNT(6);                                                                     \
    BAR; MM(1, af, bv1); BAR;                                                     \
  } while (0)

  // prologue FIFO: [A0t0, B0t0, B1t0, A1t0, A0t1, B0t1]
  STAGE_A(0, 0, 0); STAGE_B(0, 0, 0);
  STAGE_B(0, 0, 1); STAGE_A(0, 0, 1);
  STAGE_A(1, 1, 0); STAGE_B(1, 1, 0);
  VMCNT(6);
  BAR;

  for (int j = 0; j < NT_/2; ++j) {
    TILE(0, 2*j);
    TILE(1, 2*j + 1);
  }

  // swapped epilogue: row = m-dim (lo fixed), 4 consecutive cols -> 8B stores
#pragma unroll
  for (int m = 0; m < 8; ++m) {
    int row = mbase + wr*128 + m*16 + lo;
#pragma unroll
    for (int n = 0; n < 4; ++n) {
      int colb = nbase + wc*64 + n*16 + hi*4;
      float4 b4 = *(const float4*)&bias[colb];
      *(uint2*)&C[(size_t)row*D_ + colb] = make_uint2(
          cvtpk((acc[m][n][0] + b4.x) * osc, (acc[m][n][1] + b4.y) * osc),
          cvtpk((acc[m][n][2] + b4.z) * osc, (acc[m][n][3] + b4.w) * osc));
    }
  }
#undef TILE
#undef MM
#undef LDA_F
#undef LDB_F
#undef STAGE_A
#undef STAGE_B
#undef BAR
}

// ---------------- GEMM 64x128 tile (out-projection, fp32 out, swapped) ----------------
__global__ __launch_bounds__(256) void gemm_bt64(
    const u16* __restrict__ A, const u16* __restrict__ W,
    const float* __restrict__ bias, float* __restrict__ C,
    int M, int N, int K) {
  __shared__ u16 As[64*32];
  __shared__ u16 Bs[128*32];
  const int tid = threadIdx.x;
  const int wave = tid >> 6, lane = tid & 63;
  const int lo = lane & 15, hi = lane >> 4;
  const int mbase = blockIdx.y * 64, nbase = blockIdx.x * 128;

  f32x4 acc[4][2] = {};

  for (int k0 = 0; k0 < K; k0 += 32) {
    {
      int row = tid >> 2;
      int col = (tid & 3) * 8;
      gload_lds16(&A[(size_t)(mbase + row)*K + k0 + col], &As[row*32 + col]);
#pragma unroll
      for (int i = 0; i < 2; ++i)
        gload_lds16(&W[(size_t)(nbase + i*64 + row)*K + k0 + col], &Bs[(i*64 + row)*32 + col]);
    }
    __syncthreads();
    bf16x8 af[4], bfr[2];
#pragma unroll
    for (int m = 0; m < 4; ++m)
      af[m] = *(const bf16x8*)&As[(m*16 + lo)*32 + hi*8];
#pragma unroll
    for (int n = 0; n < 2; ++n)
      bfr[n] = *(const bf16x8*)&Bs[(wave*32 + n*16 + lo)*32 + hi*8];
#pragma unroll
    for (int m = 0; m < 4; ++m)
#pragma unroll
      for (int n = 0; n < 2; ++n)
        acc[m][n] = mfma16(bfr[n], af[m], acc[m][n]);   // swapped: rows=n, cols=m
    __syncthreads();
  }

#pragma unroll
  for (int m = 0; m < 4; ++m) {
    int row = mbase + m*16 + lo;
#pragma unroll
    for (int n = 0; n < 2; ++n) {
      int colb = nbase + wave*32 + n*16 + hi*4;
      float4 b4 = *(const float4*)&bias[colb];
      float4 ov = make_float4(acc[m][n][0] + b4.x, acc[m][n][1] + b4.y,
                              acc[m][n][2] + b4.z, acc[m][n][3] + b4.w);
      *(float4*)&C[(size_t)row*N + colb] = ov;
    }
  }
}

// ---------------- V [B,S,D] (head-sliced) -> Vt [B,H,DK,S] ----------------
__global__ __launch_bounds__(256) void transpose_v(const u16* __restrict__ V,
                                                   u16* __restrict__ Vt) {
  const int st = blockIdx.x, bh = blockIdx.y;
  const int b = bh >> 4, h = bh & 15;
  __shared__ u16 tile[64][72];
  const int tid = threadIdx.x;
#pragma unroll
  for (int c = 0; c < 2; ++c) {
    int s = c*32 + (tid >> 3);
    int d0 = (tid & 7) * 8;
    *(uint4*)&tile[s][d0] =
        *(const uint4*)&V[((size_t)(b*S_ + st*64 + s))*D_ + h*DK_ + d0];
  }
  __syncthreads();
#pragma unroll
  for (int c = 0; c < 2; ++c) {
    int d = c*32 + (tid >> 3);
    int s0 = (tid & 7) * 8;
    uint4 ov;
    u16* tp = (u16*)&ov;
#pragma unroll
    for (int jj = 0; jj < 8; ++jj) tp[jj] = tile[s0 + jj][d];
    *(uint4*)&Vt[((size_t)(bh*DK_ + d))*S_ + st*64 + s0] = ov;
  }
}

// ---------------- causal flash attention (QBLK=64, swapped PV, cvt_pk) ----------------
// Grid 1024 (1 q-tile/block, longest-first, XCD-clustered bh). Direct-to-LDS
// staging w/ pre-swizzled source, double-buffered, 1 barrier/iter. Swapped QK^T
// (per-lane q = lo) -> shuffle-free common path; defer-max; swapped PV -> lane-
// scalar corr and 1/l; P and AO packed via v_cvt_pk_bf16_f32.
__global__ __launch_bounds__(256) void attn_kernel(
    const u16* __restrict__ Q, const u16* __restrict__ K, const u16* __restrict__ Vt,
    u16* __restrict__ AO) {
  const int blk = blockIdx.x;
  const int xcd = blk & 7, slot = blk >> 3;   // slot 0..127
  const int bh = xcd + 8*(slot & 3);          // 4 bh per XCD
  const int qt = 31 - (slot >> 2);            // longest-first
  const int b = bh >> 4, h = bh & 15;
  const int tid = threadIdx.x, w = tid >> 6, lane = tid & 63;
  const int lo = lane & 15, hi = lane >> 4;

  __shared__ u16 Kl[2][64*64];
  __shared__ u16 Vl[2][64*64];
  __shared__ u16 Pl[4][16*72];

  const int r8 = lane >> 3;
  const int rloc = w*8 + r8;
  const int xorcol = ((lane & 7) ^ r8) * 8;
  const size_t kbase = (size_t)b*S_*D_ + (size_t)h*DK_;
  const size_t vbase = (size_t)bh*DK_*S_;
  const size_t koff0 = kbase + (size_t)rloc*D_ + xorcol;
  const size_t koff1 = kbase + (size_t)(32 + rloc)*D_ + xorcol;
  const size_t voff0 = vbase + (size_t)rloc*S_ + xorcol;
  const size_t voff1 = vbase + (size_t)(32 + rloc)*S_ + xorcol;
  const int ldsoff = rloc*64 + (lane & 7)*8;

  const int qrow = qt*64 + w*16 + lo;
  bf16x8 qf[2];
#pragma unroll
  for (int kk = 0; kk < 2; ++kk)
    qf[kk] = *(const bf16x8*)&Q[(size_t)(b*S_ + qrow)*D_ + h*DK_ + kk*32 + hi*8];

  f32x4 o[4] = {};
  float mr = -INFINITY, lr = 0.f;

  gload_lds16(&K[koff0], &Kl[0][ldsoff]);
  gload_lds16(&K[koff1], &Kl[0][2048 + ldsoff]);
  gload_lds16(&Vt[voff0], &Vl[0][ldsoff]);
  gload_lds16(&Vt[voff1], &Vl[0][2048 + ldsoff]);

  for (int kt = 0; kt <= qt; ++kt) {
    const int cur = kt & 1;
    __syncthreads();   // tile kt resident; buf cur^1 free
    if (kt < qt) {
      const size_t kadd = (size_t)(kt + 1)*64*D_;
      const int vadd = (kt + 1)*64;
      gload_lds16(&K[koff0 + kadd], &Kl[cur ^ 1][ldsoff]);
      gload_lds16(&K[koff1 + kadd], &Kl[cur ^ 1][2048 + ldsoff]);
      gload_lds16(&Vt[voff0 + vadd], &Vl[cur ^ 1][ldsoff]);
      gload_lds16(&Vt[voff1 + vadd], &Vl[cur ^ 1][2048 + ldsoff]);
    }

    // S^T = K Q^T : lane holds s[n][j] = score(q=lo, kv=n*16+hi*4+j)
    f32x4 s[4] = {};
#pragma unroll
    for (int kk = 0; kk < 2; ++kk) {
#pragma unroll
      for (int n = 0; n < 4; ++n) {
        int row = n*16 + lo;
        bf16x8 kf = *(const bf16x8*)&Kl[cur][row*64 + (((kk*4 + hi) ^ (row & 7)) * 8)];
        s[n] = mfma16(kf, qf[kk], s[n]);
      }
    }

    if (kt == qt) {  // causal mask on diagonal tile
      const int ql = w*16 + lo;
#pragma unroll
      for (int n = 0; n < 4; ++n)
#pragma unroll
        for (int j = 0; j < 4; ++j)
          if (n*16 + hi*4 + j > ql) s[n][j] = -INFINITY;
    }

    float pm = -INFINITY;
#pragma unroll
    for (int n = 0; n < 4; ++n)
#pragma unroll
      for (int j = 0; j < 4; ++j) pm = fmaxf(pm, s[n][j]);

    if (!__all(pm <= mr + 11.0f)) {   // defer-max: rescale rarely
      pm = fmaxf(pm, __shfl_xor(pm, 16));
      pm = fmaxf(pm, __shfl_xor(pm, 32));
      float mn = fmaxf(mr, pm);
      float corr = __builtin_amdgcn_exp2f(mr - mn);
      mr = mn;
      lr *= corr;
#pragma unroll
      for (int n = 0; n < 4; ++n)
#pragma unroll
        for (int j = 0; j < 4; ++j) o[n][j] *= corr;
    }

#pragma unroll
    for (int n = 0; n < 4; ++n) {
      float p0 = __builtin_amdgcn_exp2f(s[n][0] - mr);
      float p1 = __builtin_amdgcn_exp2f(s[n][1] - mr);
      float p2 = __builtin_amdgcn_exp2f(s[n][2] - mr);
      float p3 = __builtin_amdgcn_exp2f(s[n][3] - mr);
      lr += (p0 + p1) + (p2 + p3);
      *(uint2*)&Pl[w][lo*72 + n*16 + hi*4] =
          make_uint2(cvtpk(p0, p1), cvtpk(p2, p3));
    }

    // O^T += V P^T (swapped): o[n] rows = dk, cols = q (lo)
#pragma unroll
    for (int kk = 0; kk < 2; ++kk) {
      bf16x8 pf = *(const bf16x8*)&Pl[w][lo*72 + kk*32 + hi*8];
#pragma unroll
      for (int n = 0; n < 4; ++n) {
        int row = n*16 + lo;
        bf16x8 vf = *(const bf16x8*)&Vl[cur][row*64 + (((kk*4 + hi) ^ (row & 7)) * 8)];
        o[n] = mfma16(vf, pf, o[n]);
      }
    }
  }

  lr += __shfl_xor(lr, 16);
  lr += __shfl_xor(lr, 32);
  const float rinv = __builtin_amdgcn_rcpf(lr);
  const size_t obase = (size_t)(b*S_ + qrow)*D_ + h*DK_;
#pragma unroll
  for (int n = 0; n < 4; ++n) {
    *(uint2*)&AO[obase + n*16 + hi*4] =
        make_uint2(cvtpk(o[n][0] * rinv, o[n][1] * rinv),
                   cvtpk(o[n][2] * rinv, o[n][3] * rinv));
  }
}

extern "C" void kernel_launch(void* const* d_in, const int* in_sizes, int n_in,
                              void* d_out, int out_size, void* d_ws, size_t ws_size,
                              hipStream_t stream) {
  const float* x  = (const float*)d_in[0];
  const float* Wq = (const float*)d_in[1];
  const float* bq = (const float*)d_in[2];
  const float* Wk = (const float*)d_in[3];
  const float* bk = (const float*)d_in[4];
  const float* Wv = (const float*)d_in[5];
  const float* bv = (const float*)d_in[6];
  const float* Wo = (const float*)d_in[7];
  const float* bo = (const float*)d_in[8];

  char* ws = (char*)d_ws;
  const size_t MB = 1048576;
  u16* xb  = (u16*)(ws + 0);        // 8 MiB (x bf16; dead after QKV gemm)
  u16* Wqb = (u16*)(ws + 8*MB);     // 2 MiB each
  u16* Wkb = (u16*)(ws + 10*MB);
  u16* Wvb = (u16*)(ws + 12*MB);
  u16* Wob = (u16*)(ws + 14*MB);
  u16* Qb  = (u16*)(ws + 16*MB);    // 8 MiB
  u16* Kb  = (u16*)(ws + 24*MB);    // 8 MiB
  u16* Vb  = (u16*)(ws + 32*MB);    // 8 MiB row-major (dead after transpose)
  u16* Vtb = (u16*)(ws + 0);        // reuses xb slot
  u16* AOb = (u16*)(ws + 32*MB);    // reuses Vb slot

  f2bf_kernel<<<4096, 256, 0, stream>>>(x, xb, (M_*D_)/4);
  f2bf4_kernel<<<dim3(1024, 4), 256, 0, stream>>>(Wq, Wk, Wv, Wo,
                                                  Wqb, Wkb, Wvb, Wob, (D_*D_)/4);

  gemm_qkv_8ph<<<192, 512, 0, stream>>>(xb, Wqb, Wkb, Wvb, bq, bk, bv, Qb, Kb, Vb);

  transpose_v<<<dim3(32, 32), 256, 0, stream>>>(Vb, Vtb);

  attn_kernel<<<1024, 256, 0, stream>>>(Qb, Kb, Vtb, AOb);

  gemm_bt64<<<dim3(8, 64), 256, 0, stream>>>(AOb, Wob, bo, (float*)d_out, M_, D_, D_);
}